// Round 9
// baseline (438.739 us; speedup 1.0000x reference)
//
#include <hip/hip_runtime.h>
#include <hip/hip_bf16.h>
#include <stdint.h>

typedef short bhalf8 __attribute__((ext_vector_type(8)));
typedef float facc4 __attribute__((ext_vector_type(4)));

static __device__ __forceinline__ unsigned short f2bfu(float f) {
  return __builtin_bit_cast(unsigned short, __float2bfloat16(f));
}

// ---------------------------------------------------------------------------
// prep: sample conv weights w = loc + L@eps (L = tril(-1)+softplus(diag)*I)
// bf16 layout wt[a=kh*3+kw][kc=i>>5][o][i&31], bias, 16-short zero pad.
// ---------------------------------------------------------------------------
__global__ void prep_kernel(const float* __restrict__ wloc,
                            const float* __restrict__ wL,
                            const float* __restrict__ eps_w,
                            const float* __restrict__ bloc,
                            const float* __restrict__ bro,
                            const float* __restrict__ eps_b,
                            short* __restrict__ wt, float* __restrict__ bias,
                            short* __restrict__ zeros) {
  int t = blockIdx.x * 256 + threadIdx.x;  // t = o*64 + i
  int o = t >> 6, i = t & 63;
  int kc = i >> 5, il = i & 31;
  const float* Lp = wL + (size_t)t * 81;
  const float* ep = eps_w + (size_t)t * 9;
  const float* lp = wloc + (size_t)t * 9;
  float e[9];
#pragma unroll
  for (int b = 0; b < 9; ++b) e[b] = ep[b];
#pragma unroll
  for (int a = 0; a < 9; ++a) {
    float s = lp[a];
    for (int b = 0; b < a; ++b) s += Lp[a * 9 + b] * e[b];
    float d = Lp[a * 9 + a];
    float sp = (d > 20.f) ? d : log1pf(expf(d));
    s += sp * e[a];
    wt[((a * 2 + kc) * 64 + o) * 32 + il] = (short)f2bfu(s);
  }
  if (t < 64) {
    float d = bro[t];
    float sp = (d > 20.f) ? d : log1pf(expf(d));
    bias[t] = bloc[t] + eps_b[t] * sp;
  }
  if (t < 16) zeros[t] = 0;
}

// ---------------------------------------------------------------------------
// pass 1: x NCHW f32 -> NHWC bf16 ([n][p=h*224+w][c64]). Streaming ~5.4 TB/s.
// ---------------------------------------------------------------------------
__global__ __launch_bounds__(512) void to_nhwc_kernel(
    const float* __restrict__ x, short* __restrict__ xh) {
  int b = blockIdx.x;
  int n = b / 196;
  int p0 = (b % 196) * 256;
  int t = threadIdx.x;
  int pl = t >> 3, c8 = t & 7;
  const float* xp = x + (size_t)(n * 64 + c8 * 8) * 50176 + p0 + pl * 4;
  short* op = xh + ((size_t)n * 50176 + p0 + pl * 4) * 64 + c8 * 8;
  float4 v[8];
#pragma unroll
  for (int j = 0; j < 8; ++j) v[j] = *(const float4*)(xp + (size_t)j * 50176);
#pragma unroll
  for (int s = 0; s < 4; ++s) {
    bhalf8 h;
#pragma unroll
    for (int j = 0; j < 8; ++j) h[j] = f2bfu(((const float*)&v[j])[s]);
    *(bhalf8*)(op + s * 64) = h;
  }
}

// ---------------------------------------------------------------------------
// pass 2: one-shot small-tile conv. Block = 4 waves (256 thr), tile
// 64o x 4 rows x 32 px, ALL 64 channels staged at once (full 128B/pixel
// lines -> half the DMA transactions of the 32ch split). LDS [6r][34cc][64ch]
// = 26.1 KB -> 6 blocks/CU (24 waves): phase overlap via independent blocks
// (R6-proven regime), ONE barrier per block. acc[4][2] = 32 AGPR + VGPR<=53
// fits (256,6) budget. Channel-group XOR swizzle (chunk gd holds channel
// gd^(cc&7); linear DMA dest + permuted SOURCE, same XOR on read): B-frag
// ds_read_b128 spreads 16 lanes over 8 x 16B slots = 2-way broadcast, free.
// Grid 12544 = 56ht x 7wc x 32n, XCD-chunked (n-banded per XCD, L3-friendly).
// ---------------------------------------------------------------------------
__global__ __launch_bounds__(256, 6) void conv_tile_kernel(
    const short* __restrict__ xh, const short* __restrict__ wt,
    const float* __restrict__ bias, const short* __restrict__ zeros,
    float* __restrict__ out) {
  __shared__ short lds[6 * 34 * 64];  // 26112 B
  int b0 = blockIdx.x;
  int b = (b0 & 7) * 1568 + (b0 >> 3);  // bijective: 12544 % 8 == 0
  int ht = b % 56;
  int rest = b / 56;
  int wc = rest % 7, n = rest / 7;
  int h0 = ht * 4, w0 = wc * 32;
  int t = threadIdx.x, lane = t & 63, wv = t >> 6;  // wv 0..3
  int l15 = lane & 15, l4 = lane >> 4;

  // ---- stage: 1632 16B chunks, id=(r*34+cc)*8+gd, data ch-group gd^(cc&7)
  const size_t nb = (size_t)n * 3211264;
#pragma unroll
  for (int k = 0; k < 7; ++k) {
    int id = k * 256 + t;
    if (id < 1632) {
      int gd = id & 7;
      int pc = id >> 3;
      int cc = pc % 34, r = pc / 34;
      int g = gd ^ (cc & 7);
      int h_in = h0 - 1 + r, w_in = w0 - 1 + cc;
      const short* src = (h_in >= 0 && h_in < 224 && w_in >= 0 && w_in < 224)
                             ? xh + nb + (size_t)(h_in * 224 + w_in) * 64 +
                                   g * 8
                             : zeros;
      __builtin_amdgcn_global_load_lds(
          (const __attribute__((address_space(1))) void*)src,
          (__attribute__((address_space(3))) void*)(lds +
                                                    (k * 256 + wv * 64) * 8),
          16, 0, 0);
    }
  }
  __syncthreads();

  // ---- compute: 9 taps x K=64 (2 x K=32 MFMA), 144 MFMA/wave ----
  facc4 acc[4][2];
#pragma unroll
  for (int om = 0; om < 4; ++om)
#pragma unroll
    for (int p = 0; p < 2; ++p) {
      facc4 z = {0.f, 0.f, 0.f, 0.f};
      acc[om][p] = z;
    }

#pragma unroll
  for (int kh = 0; kh < 3; ++kh) {
    int r = wv + kh;  // staged row for this wave's out row
#pragma unroll
    for (int kw = 0; kw < 3; ++kw) {
#pragma unroll
      for (int kc = 0; kc < 2; ++kc) {
        const short* wb =
            wt + (((kh * 3 + kw) * 2 + kc) * 64 + l15) * 32 + (l4 << 3);
        bhalf8 a[4];
#pragma unroll
        for (int om = 0; om < 4; ++om)
          a[om] = *(const bhalf8*)(wb + om * 512);
#pragma unroll
        for (int p = 0; p < 2; ++p) {
          int tc = p * 16 + l15 + kw;  // 0..33
          int chunk = (r * 34 + tc) * 8 + ((kc * 4 + l4) ^ (tc & 7));
          bhalf8 bv = *(const bhalf8*)(lds + chunk * 8);
#pragma unroll
          for (int om = 0; om < 4; ++om)
            acc[om][p] = __builtin_amdgcn_mfma_f32_16x16x32_bf16(
                a[om], bv, acc[om][p], 0, 0, 0);
        }
      }
    }
  }

  // ---- epilogue: D[o=om*16+l4*4+jj][px=p*16+l15], w0+31 <= 223 no guard ----
  int h = h0 + wv;
#pragma unroll
  for (int om = 0; om < 4; ++om) {
#pragma unroll
    for (int jj = 0; jj < 4; ++jj) {
      int o = om * 16 + l4 * 4 + jj;
      float bo = bias[o];
      float* op = out + ((size_t)(n * 64 + o) * 224 + h) * 224 + w0;
#pragma unroll
      for (int p = 0; p < 2; ++p) op[p * 16 + l15] = acc[om][p][jj] + bo;
    }
  }
}

// ---------------------------------------------------------------------------
// fallback (ws too small): R5 one-pass kernel (proven, 460 us).
// ---------------------------------------------------------------------------
typedef unsigned int uintv2 __attribute__((ext_vector_type(2)));
#define LD1(cj, i)                                                   \
  ((hok && (w_in0 + (i)) >= 0 && (w_in0 + (i)) < 224)                \
       ? cbase[(size_t)(cj) * 50176 + w_in0 + (i)]                   \
       : 0.f)

__global__ __launch_bounds__(256, 4) void conv_onepass_kernel(
    const float* __restrict__ x, const short* __restrict__ wt,
    const float* __restrict__ bias, float* __restrict__ out) {
  __shared__ short lds[6 * 66 * 32];
  int b0 = blockIdx.x;
  int b = (b0 & 7) * 896 + (b0 >> 3);
  int ht = b % 56;
  int rest = b / 56;
  int w4 = rest & 3, n = rest >> 2;
  int h0 = ht * 4, w0 = w4 * 64;
  int t = threadIdx.x, lane = t & 63, wv = t >> 6;
  int l15 = lane & 15, l4 = lane >> 4;

  facc4 acc[4][4];
#pragma unroll
  for (int om = 0; om < 4; ++om)
#pragma unroll
    for (int p = 0; p < 4; ++p) {
      facc4 z = {0.f, 0.f, 0.f, 0.f};
      acc[om][p] = z;
    }

  for (int ic = 0; ic < 2; ++ic) {
#pragma unroll
    for (int k = 0; k < 4; ++k) {
      int u = t + k * 256;
      if (u < 816) {
        int chg = u & 7;
        int tmp = u >> 3;
        int ccg = tmp % 17, r = tmp / 17;
        int h_in = h0 - 1 + r;
        bool hok = (h_in >= 0) & (h_in < 224);
        int w_in0 = w0 - 1 + ccg * 4;
        int ch0 = ic * 32 + chg * 4;
        const float* cbase =
            x + ((size_t)(n * 64 + ch0) * 224 + (hok ? h_in : 0)) * 224;
        float4 v0, v1, v2, v3;
        if (hok && w_in0 >= 0 && w_in0 + 3 < 224) {
          v0 = *(const float4*)(cbase + w_in0);
          v1 = *(const float4*)(cbase + 50176 + w_in0);
          v2 = *(const float4*)(cbase + 2 * 50176 + w_in0);
          v3 = *(const float4*)(cbase + 3 * 50176 + w_in0);
        } else {
          v0 = make_float4(LD1(0, 0), LD1(0, 1), LD1(0, 2), LD1(0, 3));
          v1 = make_float4(LD1(1, 0), LD1(1, 1), LD1(1, 2), LD1(1, 3));
          v2 = make_float4(LD1(2, 0), LD1(2, 1), LD1(2, 2), LD1(2, 3));
          v3 = make_float4(LD1(3, 0), LD1(3, 1), LD1(3, 2), LD1(3, 3));
        }
        int g = chg >> 1;
        int halfsel = (chg & 1) << 2;
#pragma unroll
        for (int i = 0; i < 4; ++i) {
          int cc = ccg * 4 + i;
          if (cc < 66) {
            float a0 = ((const float*)&v0)[i], a1 = ((const float*)&v1)[i];
            float a2 = ((const float*)&v2)[i], a3 = ((const float*)&v3)[i];
            unsigned int w0p =
                (unsigned int)f2bfu(a0) | ((unsigned int)f2bfu(a1) << 16);
            unsigned int w1p =
                (unsigned int)f2bfu(a2) | ((unsigned int)f2bfu(a3) << 16);
            int addr =
                (r * 66 + cc) * 32 + ((g ^ ((cc >> 1) & 3)) << 3) + halfsel;
            uintv2 pk = {w0p, w1p};
            *(uintv2*)(lds + addr) = pk;
          }
        }
      }
    }
    __syncthreads();
#pragma unroll
    for (int kh = 0; kh < 3; ++kh) {
      int r = wv + kh;
#pragma unroll
      for (int kw = 0; kw < 3; ++kw) {
        const short* wb =
            wt + (((kh * 3 + kw) * 2 + ic) * 64 + l15) * 32 + (l4 << 3);
        bhalf8 a[4];
#pragma unroll
        for (int om = 0; om < 4; ++om)
          a[om] = *(const bhalf8*)(wb + om * 512);
#pragma unroll
        for (int p = 0; p < 4; ++p) {
          int tc = p * 16 + l15 + kw;
          bhalf8 bv = *(const bhalf8*)(lds + (r * 66 + tc) * 32 +
                                       ((l4 ^ ((tc >> 1) & 3)) << 3));
#pragma unroll
          for (int om = 0; om < 4; ++om)
            acc[om][p] = __builtin_amdgcn_mfma_f32_16x16x32_bf16(
                a[om], bv, acc[om][p], 0, 0, 0);
        }
      }
    }
    if (ic == 0) __syncthreads();
  }

  int h = h0 + wv;
#pragma unroll
  for (int om = 0; om < 4; ++om) {
#pragma unroll
    for (int j = 0; j < 4; ++j) {
      int o = om * 16 + l4 * 4 + j;
      float bo = bias[o];
      float* op = out + ((size_t)(n * 64 + o) * 224 + h) * 224 + w0;
#pragma unroll
      for (int p = 0; p < 4; ++p) {
        int wg = w0 + p * 16 + l15;
        if (wg < 224) op[p * 16 + l15] = acc[om][p][j] + bo;
      }
    }
  }
}

extern "C" void kernel_launch(void* const* d_in, const int* in_sizes, int n_in,
                              void* d_out, int out_size, void* d_ws,
                              size_t ws_size, hipStream_t stream) {
  const float* x = (const float*)d_in[0];
  const float* wloc = (const float*)d_in[1];
  const float* wL = (const float*)d_in[2];
  const float* bloc = (const float*)d_in[3];
  const float* bro = (const float*)d_in[4];
  const float* eps_w = (const float*)d_in[5];
  const float* eps_b = (const float*)d_in[6];
  float* outp = (float*)d_out;

  short* wt = (short*)d_ws;                      // 73728 B
  float* bias = (float*)((char*)d_ws + 73728);   // 64 f32
  short* zeros = (short*)((char*)d_ws + 73984);  // 16 bf16 zero pad
  short* xh = (short*)((char*)d_ws + 74240);     // 205.5 MB
  const size_t need = 74240ull + (size_t)32 * 50176 * 64 * 2;

  prep_kernel<<<16, 256, 0, stream>>>(wloc, wL, eps_w, bloc, bro, eps_b, wt,
                                      bias, zeros);
  if (ws_size >= need) {
    to_nhwc_kernel<<<32 * 196, 512, 0, stream>>>(x, xh);
    conv_tile_kernel<<<12544, 256, 0, stream>>>(xh, wt, bias, zeros, outp);
  } else {
    conv_onepass_kernel<<<7168, 256, 0, stream>>>(x, wt, bias, outp);
  }
}

// Round 10
// 343.551 us; speedup vs baseline: 1.2771x; 1.2771x over previous
//
#include <hip/hip_runtime.h>
#include <hip/hip_bf16.h>
#include <stdint.h>

typedef short bhalf8 __attribute__((ext_vector_type(8)));
typedef float facc4 __attribute__((ext_vector_type(4)));

static __device__ __forceinline__ unsigned short f2bfu(float f) {
  return __builtin_bit_cast(unsigned short, __float2bfloat16(f));
}

// ---------------------------------------------------------------------------
// prep: sample conv weights w = loc + L@eps (L = tril(-1)+softplus(diag)*I)
// bf16 layout wt[a=kh*3+kw][kc=i>>5][o][i&31], bias, 16-short zero pad.
// ---------------------------------------------------------------------------
__global__ void prep_kernel(const float* __restrict__ wloc,
                            const float* __restrict__ wL,
                            const float* __restrict__ eps_w,
                            const float* __restrict__ bloc,
                            const float* __restrict__ bro,
                            const float* __restrict__ eps_b,
                            short* __restrict__ wt, float* __restrict__ bias,
                            short* __restrict__ zeros) {
  int t = blockIdx.x * 256 + threadIdx.x;  // t = o*64 + i
  int o = t >> 6, i = t & 63;
  int kc = i >> 5, il = i & 31;
  const float* Lp = wL + (size_t)t * 81;
  const float* ep = eps_w + (size_t)t * 9;
  const float* lp = wloc + (size_t)t * 9;
  float e[9];
#pragma unroll
  for (int b = 0; b < 9; ++b) e[b] = ep[b];
#pragma unroll
  for (int a = 0; a < 9; ++a) {
    float s = lp[a];
    for (int b = 0; b < a; ++b) s += Lp[a * 9 + b] * e[b];
    float d = Lp[a * 9 + a];
    float sp = (d > 20.f) ? d : log1pf(expf(d));
    s += sp * e[a];
    wt[((a * 2 + kc) * 64 + o) * 32 + il] = (short)f2bfu(s);
  }
  if (t < 64) {
    float d = bro[t];
    float sp = (d > 20.f) ? d : log1pf(expf(d));
    bias[t] = bloc[t] + eps_b[t] * sp;
  }
  if (t < 16) zeros[t] = 0;
}

// ---------------------------------------------------------------------------
// pass 1: x NCHW f32 -> NHWC bf16 ([n][p=h*224+w][c64]). Streaming ~5.4 TB/s.
// ---------------------------------------------------------------------------
__global__ __launch_bounds__(512) void to_nhwc_kernel(
    const float* __restrict__ x, short* __restrict__ xh) {
  int b = blockIdx.x;
  int n = b / 196;
  int p0 = (b % 196) * 256;
  int t = threadIdx.x;
  int pl = t >> 3, c8 = t & 7;
  const float* xp = x + (size_t)(n * 64 + c8 * 8) * 50176 + p0 + pl * 4;
  short* op = xh + ((size_t)n * 50176 + p0 + pl * 4) * 64 + c8 * 8;
  float4 v[8];
#pragma unroll
  for (int j = 0; j < 8; ++j) v[j] = *(const float4*)(xp + (size_t)j * 50176);
#pragma unroll
  for (int s = 0; s < 4; ++s) {
    bhalf8 h;
#pragma unroll
    for (int j = 0; j < 8; ++j) h[j] = f2bfu(((const float*)&v[j])[s]);
    *(bhalf8*)(op + s * 64) = h;
  }
}

// ---------------------------------------------------------------------------
// pass 2: R6 structure + WEIGHTS IN LDS. Block = 8 waves, 64o x 8r x 64px,
// 2 ic-rounds. Per round DMA-stage: x-tile [10r][4g][66cc][8ch] (2640 chunks,
// R6-proven) + wt half [9a][64o][32k] (2304 chunks, 36.9 KB from L2/L3-hot
// 73.7 KB region). LDS 79.1 KB -> 2 blocks/CU (VGPR<=64 + 64 acc). A-frags
// now dense 1KB/wave ds_read_b128 (conflict-free) instead of global L2-hit
// ~200cyc (73.7KB > 32KB L1 = thrash -> the R1-R9 latency wall).
// Grid 3584 = vertical-adjacent consecutive + XCD chunk (halo L2 reuse).
// ---------------------------------------------------------------------------
__global__ __launch_bounds__(512, 4) void conv_awt_kernel(
    const short* __restrict__ xh, const short* __restrict__ wtg,
    const float* __restrict__ bias, const short* __restrict__ zeros,
    float* __restrict__ out) {
  extern __shared__ short smem[];
  short* lds_x = smem;          // 2640 chunks * 8 shorts = 42240 B
  short* lds_w = smem + 21120;  // 2304 chunks * 8 shorts = 36864 B

  int b0 = blockIdx.x;
  int b = (b0 & 7) * 448 + (b0 >> 3);  // bijective: 3584 % 8 == 0
  int ht = b % 28;
  int rest = b / 28;
  int w4 = rest & 3, n = rest >> 2;
  int h0 = ht * 8, w0 = w4 * 64;
  int t = threadIdx.x, lane = t & 63, wv = t >> 6;
  int l15 = lane & 15, l4 = lane >> 4;

  facc4 acc[4][4];
#pragma unroll
  for (int om = 0; om < 4; ++om)
#pragma unroll
    for (int p = 0; p < 4; ++p) {
      facc4 z = {0.f, 0.f, 0.f, 0.f};
      acc[om][p] = z;
    }

  const size_t nbase = (size_t)n * 50176 * 64;
  for (int ic = 0; ic < 2; ++ic) {
    // ---- stage x: 2640 16B chunks, id=(r*4+g)*66+cc (R6-proven) ----
#pragma unroll
    for (int k = 0; k < 6; ++k) {
      int id = k * 512 + t;
      if (id < 2640) {
        int cc = id % 66;
        int rg = id / 66;
        int g = rg & 3, r = rg >> 2;
        int h_in = h0 - 1 + r, w_in = w0 - 1 + cc;
        const short* src =
            (h_in >= 0 && h_in < 224 && w_in >= 0 && w_in < 224)
                ? xh + nbase + (size_t)(h_in * 224 + w_in) * 64 + ic * 32 +
                      g * 8
                : zeros;
        __builtin_amdgcn_global_load_lds(
            (const __attribute__((address_space(1))) void*)src,
            (__attribute__((address_space(3))) void*)((char*)lds_x +
                                                      (k * 512 + wv * 64) *
                                                          16),
            16, 0, 0);
      }
    }
    // ---- stage wt half: 2304 16B chunks, [a][o][k32] for this ic ----
#pragma unroll
    for (int k = 0; k < 5; ++k) {
      int w = k * 512 + t;
      if (w < 2304) {
        const short* src = wtg + (w >> 8) * 4096 + ic * 2048 + (w & 255) * 8;
        __builtin_amdgcn_global_load_lds(
            (const __attribute__((address_space(1))) void*)src,
            (__attribute__((address_space(3))) void*)((char*)lds_w +
                                                      (k * 512 + wv * 64) *
                                                          16),
            16, 0, 0);
      }
    }
    __syncthreads();
    // ---- compute: 9 shifted positions, K=32 each; A and B from LDS ----
#pragma unroll
    for (int kh = 0; kh < 3; ++kh) {
      int r = wv + kh;
#pragma unroll
      for (int kw = 0; kw < 3; ++kw) {
        const int tap = kh * 3 + kw;
        const short* ab = lds_w + tap * 2048 + l15 * 32 + (l4 << 3);
        bhalf8 a[4];
#pragma unroll
        for (int om = 0; om < 4; ++om)
          a[om] = *(const bhalf8*)(ab + om * 512);
#pragma unroll
        for (int p = 0; p < 4; ++p) {
          int tc = p * 16 + l15 + kw;
          bhalf8 bv = *(const bhalf8*)(lds_x + (((r * 4 + l4) * 66) + tc) * 8);
#pragma unroll
          for (int om = 0; om < 4; ++om)
            acc[om][p] = __builtin_amdgcn_mfma_f32_16x16x32_bf16(
                a[om], bv, acc[om][p], 0, 0, 0);
        }
      }
    }
    if (ic == 0) __syncthreads();
  }

  // ---- epilogue: D[o=om*16+l4*4+jj][px=p*16+l15] + bias, NCHW f32 out ----
  int h = h0 + wv;
#pragma unroll
  for (int om = 0; om < 4; ++om) {
#pragma unroll
    for (int jj = 0; jj < 4; ++jj) {
      int o = om * 16 + l4 * 4 + jj;
      float bo = bias[o];
      float* op = out + ((size_t)(n * 64 + o) * 224 + h) * 224 + w0;
#pragma unroll
      for (int p = 0; p < 4; ++p) {
        int wg = w0 + p * 16 + l15;
        if (wg < 224) op[p * 16 + l15] = acc[om][p][jj] + bo;
      }
    }
  }
}

// ---------------------------------------------------------------------------
// fallback (ws too small): R5 one-pass kernel (proven, 460 us).
// ---------------------------------------------------------------------------
typedef unsigned int uintv2 __attribute__((ext_vector_type(2)));
#define LD1(cj, i)                                                   \
  ((hok && (w_in0 + (i)) >= 0 && (w_in0 + (i)) < 224)                \
       ? cbase[(size_t)(cj) * 50176 + w_in0 + (i)]                   \
       : 0.f)

__global__ __launch_bounds__(256, 4) void conv_onepass_kernel(
    const float* __restrict__ x, const short* __restrict__ wt,
    const float* __restrict__ bias, float* __restrict__ out) {
  __shared__ short lds[6 * 66 * 32];
  int b0 = blockIdx.x;
  int b = (b0 & 7) * 896 + (b0 >> 3);
  int ht = b % 56;
  int rest = b / 56;
  int w4 = rest & 3, n = rest >> 2;
  int h0 = ht * 4, w0 = w4 * 64;
  int t = threadIdx.x, lane = t & 63, wv = t >> 6;
  int l15 = lane & 15, l4 = lane >> 4;

  facc4 acc[4][4];
#pragma unroll
  for (int om = 0; om < 4; ++om)
#pragma unroll
    for (int p = 0; p < 4; ++p) {
      facc4 z = {0.f, 0.f, 0.f, 0.f};
      acc[om][p] = z;
    }

  for (int ic = 0; ic < 2; ++ic) {
#pragma unroll
    for (int k = 0; k < 4; ++k) {
      int u = t + k * 256;
      if (u < 816) {
        int chg = u & 7;
        int tmp = u >> 3;
        int ccg = tmp % 17, r = tmp / 17;
        int h_in = h0 - 1 + r;
        bool hok = (h_in >= 0) & (h_in < 224);
        int w_in0 = w0 - 1 + ccg * 4;
        int ch0 = ic * 32 + chg * 4;
        const float* cbase =
            x + ((size_t)(n * 64 + ch0) * 224 + (hok ? h_in : 0)) * 224;
        float4 v0, v1, v2, v3;
        if (hok && w_in0 >= 0 && w_in0 + 3 < 224) {
          v0 = *(const float4*)(cbase + w_in0);
          v1 = *(const float4*)(cbase + 50176 + w_in0);
          v2 = *(const float4*)(cbase + 2 * 50176 + w_in0);
          v3 = *(const float4*)(cbase + 3 * 50176 + w_in0);
        } else {
          v0 = make_float4(LD1(0, 0), LD1(0, 1), LD1(0, 2), LD1(0, 3));
          v1 = make_float4(LD1(1, 0), LD1(1, 1), LD1(1, 2), LD1(1, 3));
          v2 = make_float4(LD1(2, 0), LD1(2, 1), LD1(2, 2), LD1(2, 3));
          v3 = make_float4(LD1(3, 0), LD1(3, 1), LD1(3, 2), LD1(3, 3));
        }
        int g = chg >> 1;
        int halfsel = (chg & 1) << 2;
#pragma unroll
        for (int i = 0; i < 4; ++i) {
          int cc = ccg * 4 + i;
          if (cc < 66) {
            float a0 = ((const float*)&v0)[i], a1 = ((const float*)&v1)[i];
            float a2 = ((const float*)&v2)[i], a3 = ((const float*)&v3)[i];
            unsigned int w0p =
                (unsigned int)f2bfu(a0) | ((unsigned int)f2bfu(a1) << 16);
            unsigned int w1p =
                (unsigned int)f2bfu(a2) | ((unsigned int)f2bfu(a3) << 16);
            int addr =
                (r * 66 + cc) * 32 + ((g ^ ((cc >> 1) & 3)) << 3) + halfsel;
            uintv2 pk = {w0p, w1p};
            *(uintv2*)(lds + addr) = pk;
          }
        }
      }
    }
    __syncthreads();
#pragma unroll
    for (int kh = 0; kh < 3; ++kh) {
      int r = wv + kh;
#pragma unroll
      for (int kw = 0; kw < 3; ++kw) {
        const short* wb =
            wt + (((kh * 3 + kw) * 2 + ic) * 64 + l15) * 32 + (l4 << 3);
        bhalf8 a[4];
#pragma unroll
        for (int om = 0; om < 4; ++om)
          a[om] = *(const bhalf8*)(wb + om * 512);
#pragma unroll
        for (int p = 0; p < 4; ++p) {
          int tc = p * 16 + l15 + kw;
          bhalf8 bv = *(const bhalf8*)(lds + (r * 66 + tc) * 32 +
                                       ((l4 ^ ((tc >> 1) & 3)) << 3));
#pragma unroll
          for (int om = 0; om < 4; ++om)
            acc[om][p] = __builtin_amdgcn_mfma_f32_16x16x32_bf16(
                a[om], bv, acc[om][p], 0, 0, 0);
        }
      }
    }
    if (ic == 0) __syncthreads();
  }

  int h = h0 + wv;
#pragma unroll
  for (int om = 0; om < 4; ++om) {
#pragma unroll
    for (int j = 0; j < 4; ++j) {
      int o = om * 16 + l4 * 4 + j;
      float bo = bias[o];
      float* op = out + ((size_t)(n * 64 + o) * 224 + h) * 224 + w0;
#pragma unroll
      for (int p = 0; p < 4; ++p) {
        int wg = w0 + p * 16 + l15;
        if (wg < 224) op[p * 16 + l15] = acc[om][p][j] + bo;
      }
    }
  }
}

extern "C" void kernel_launch(void* const* d_in, const int* in_sizes, int n_in,
                              void* d_out, int out_size, void* d_ws,
                              size_t ws_size, hipStream_t stream) {
  const float* x = (const float*)d_in[0];
  const float* wloc = (const float*)d_in[1];
  const float* wL = (const float*)d_in[2];
  const float* bloc = (const float*)d_in[3];
  const float* bro = (const float*)d_in[4];
  const float* eps_w = (const float*)d_in[5];
  const float* eps_b = (const float*)d_in[6];
  float* outp = (float*)d_out;

  short* wt = (short*)d_ws;                      // 73728 B
  float* bias = (float*)((char*)d_ws + 73728);   // 64 f32
  short* zeros = (short*)((char*)d_ws + 73984);  // 16 bf16 zero pad
  short* xh = (short*)((char*)d_ws + 74240);     // 205.5 MB
  const size_t need = 74240ull + (size_t)32 * 50176 * 64 * 2;

  prep_kernel<<<16, 256, 0, stream>>>(wloc, wL, eps_w, bloc, bro, eps_b, wt,
                                      bias, zeros);
  if (ws_size >= need) {
    to_nhwc_kernel<<<32 * 196, 512, 0, stream>>>(x, xh);
    const int dyn_lds = (21120 + 18432) * 2;  // 79104 B
    hipFuncSetAttribute((const void*)conv_awt_kernel,
                        hipFuncAttributeMaxDynamicSharedMemorySize, dyn_lds);
    conv_awt_kernel<<<3584, 512, dyn_lds, stream>>>(xh, wt, bias, zeros, outp);
  } else {
    conv_onepass_kernel<<<7168, 256, 0, stream>>>(x, wt, bias, outp);
  }
}